// Round 5
// baseline (755.104 us; speedup 1.0000x reference)
//
#include <hip/hip_runtime.h>

// WaveCell v5: 2D staggered-grid elastic FDTD timestep, fused single kernel.
// B=4, NZ=NX=2048, fp32, periodic wrap (pow2 dims).
//
// History:
//  v2 (212us): thread = 4x * 4shots, unroll 1, no swizzle. FETCH 470MB.
//  v3 (253us): +swizzle +unroll2 -> unroll2 regression.
//  v4 (213us): swizzle + unroll1. FETCH 199MB but time = v2 ->
//      NOT HBM-volume bound. VALUBusy 8.7%, occupancy 32% (VGPR 68 > 64
//      -> 4 waves/SIMD), latency-bound: burst/drain per shot + NT-store
//      acks serialized into next shot's vmcnt wait.
//  v5: thread = 4x * ONE shot (grid x4, 16384 blocks). Shot = fastest block
//      bits so same-tile blocks share an XCD (coeff re-reads = L2 hits).
//      __launch_bounds__(256,8) caps VGPR at 64 -> 8 waves/SIMD.
//      Stores now terminal (no store->load vmcnt chain). Swizzle kept.

constexpr int NZ = 2048;
constexpr int NX = 2048;
constexpr int B  = 4;
constexpr int PLANE = NZ * NX;      // 4,194,304
constexpr int VOL   = B * PLANE;    // 16,777,216
constexpr float DT    = 1e-3f;
constexpr float INV_H = 0.1f;       // 1/10m
constexpr int NBLK  = B * (PLANE / 4) / 256;   // 16384
constexpr int NXCD  = 8;
constexpr int BLK_PER_XCD = NBLK / NXCD;       // 2048

typedef float f32x4 __attribute__((ext_vector_type(4)));

__device__ __forceinline__ float rcpf(float x) { return __builtin_amdgcn_rcpf(x); }
__device__ __forceinline__ float4 ld4(const float* __restrict__ p) {
    return *reinterpret_cast<const float4*>(p);
}
__device__ __forceinline__ void st_nt4(float* __restrict__ p,
                                       float a, float b, float c, float d) {
    f32x4 v = {a, b, c, d};
    __builtin_nontemporal_store(v, reinterpret_cast<f32x4*>(p));
}

__global__ __launch_bounds__(256, 8) void wave_fused_v5(
    const float* __restrict__ vp,  const float* __restrict__ vs,
    const float* __restrict__ rho,
    const float* __restrict__ vx,  const float* __restrict__ vz,
    const float* __restrict__ txx, const float* __restrict__ tzz,
    const float* __restrict__ txz,
    const float* __restrict__ dd,
    float* __restrict__ out)
{
    // XCD-band swizzle over 16384 blocks: XCD k owns sb in [k*2048,(k+1)*2048)
    // = 512 spatial tiles (256 z-rows) x 4 shots. Shot = sb&3 (fastest) so the
    // 4 shots of one tile are dispatch-adjacent -> same XCD -> coefficient
    // rows L2-hit on re-read.
    const int bid  = blockIdx.x;
    const int sb   = (bid & (NXCD - 1)) * BLK_PER_XCD + (bid >> 3);
    const int shot = sb & 3;
    const int ts   = (sb >> 2) * blockDim.x + threadIdx.x;  // [0, PLANE/4)
    const int xg = (ts & (NX / 4 - 1)) << 2;                // x base, %4==0
    const int z  = ts >> 9;                                 // ts / (NX/4)
    const int zp = (z + 1) & (NZ - 1);
    const int zm = (z - 1) & (NZ - 1);
    const int xm1 = (xg - 1) & (NX - 1);
    const int xp4 = (xg + 4) & (NX - 1);
    const int rz  = z  * NX;
    const int rzp = zp * NX;
    const int rzm = zm * NX;
    const int b3  = shot * PLANE;
    const int cz  = b3 + rz  + xg;
    const int czp = b3 + rzp + xg;
    const int czm = b3 + rzm + xg;

    // ---------- field loads (issued first: longest latency chains) ----------
    float txxz[6], txzz[6], tzzz[5], tzzzp[5], txxzp[5];
    float txzzm[5];                 // index k <-> column xg+k
    float vxz[5];                   // index k <-> column xg+k
    float vzz[5];                   // index j <-> column xg-1+j
    {
        float4 m;
        m = ld4(txx + cz);
        txxz[1] = m.x; txxz[2] = m.y; txxz[3] = m.z; txxz[4] = m.w;
        txxz[0] = txx[b3 + rz + xm1];  txxz[5] = txx[b3 + rz + xp4];
        m = ld4(txz + cz);
        txzz[1] = m.x; txzz[2] = m.y; txzz[3] = m.z; txzz[4] = m.w;
        txzz[0] = txz[b3 + rz + xm1];  txzz[5] = txz[b3 + rz + xp4];
        m = ld4(tzz + cz);
        tzzz[1] = m.x; tzzz[2] = m.y; tzzz[3] = m.z; tzzz[4] = m.w;
        tzzz[0] = tzz[b3 + rz + xm1];
        m = ld4(tzz + czp);
        tzzzp[1] = m.x; tzzzp[2] = m.y; tzzzp[3] = m.z; tzzzp[4] = m.w;
        tzzzp[0] = tzz[b3 + rzp + xm1];
        m = ld4(txx + czp);
        txxzp[1] = m.x; txxzp[2] = m.y; txxzp[3] = m.z; txxzp[4] = m.w;
        txxzp[0] = txx[b3 + rzp + xm1];
        m = ld4(txz + czm);
        txzzm[0] = m.x; txzzm[1] = m.y; txzzm[2] = m.z; txzzm[3] = m.w;
        txzzm[4] = txz[b3 + rzm + xp4];
        m = ld4(vx + cz);
        vxz[0] = m.x; vxz[1] = m.y; vxz[2] = m.z; vxz[3] = m.w;
        vxz[4] = vx[b3 + rz + xp4];
        m = ld4(vz + cz);
        vzz[1] = m.x; vzz[2] = m.y; vzz[3] = m.z; vzz[4] = m.w;
        vzz[0] = vz[b3 + rz + xm1];
    }
    const float4 tp4  = ld4(txz + czp);  // txz row zp, cols xg..xg+3
    const float4 tm4  = ld4(tzz + czm);  // tzz row zm, cols xg..xg+3
    const float4 vxp4 = ld4(vx + czp);   // vx  row zp, cols xg..xg+3
    const float4 vzm4 = ld4(vz + czm);   // vz  row zm, cols xg..xg+3
    const float txzzp[4] = {tp4.x, tp4.y, tp4.z, tp4.w};
    const float tzzzm[4] = {tm4.x, tm4.y, tm4.z, tm4.w};
    const float vxzp[4]  = {vxp4.x, vxp4.y, vxp4.z, vxp4.w};
    const float vzzm[4]  = {vzm4.x, vzm4.y, vzm4.z, vzm4.w};

    // ---------- 2D coefficients (one shot; recomputed per shot-block) ----------
    float dz6[6], rz6[6];
    {
        const float4 d4 = ld4(dd + rz + xg);
        dz6[0] = dd[rz + xm1]; dz6[1] = d4.x; dz6[2] = d4.y;
        dz6[3] = d4.z;         dz6[4] = d4.w; dz6[5] = dd[rz + xp4];
        const float4 r4 = ld4(rho + rz + xg);
        rz6[0] = rho[rz + xm1]; rz6[1] = r4.x; rz6[2] = r4.y;
        rz6[3] = r4.z;          rz6[4] = r4.w; rz6[5] = rho[rz + xp4];
    }
    float avz[6], bvz[6], inv_c[4];
    #pragma unroll
    for (int j = 0; j < 6; ++j) {
        const float c   = 0.5f * DT * dz6[j];
        const float inv = rcpf(1.0f + c);
        avz[j] = (1.0f - c) * inv;
        bvz[j] = DT * INV_H * inv * rcpf(rz6[j]);
        if (j >= 1 && j <= 4) inv_c[j - 1] = inv;   // static after unroll
    }
    float avzp[4], bvzp[4], avzm[4], bvzm[4];
    {
        const float4 dp = ld4(dd + rzp + xg), dm = ld4(dd + rzm + xg);
        const float4 rp = ld4(rho + rzp + xg), rm = ld4(rho + rzm + xg);
        const float dpa[4] = {dp.x, dp.y, dp.z, dp.w};
        const float dma[4] = {dm.x, dm.y, dm.z, dm.w};
        const float rpa[4] = {rp.x, rp.y, rp.z, rp.w};
        const float rma[4] = {rm.x, rm.y, rm.z, rm.w};
        #pragma unroll
        for (int k = 0; k < 4; ++k) {
            float c = 0.5f * DT * dpa[k];
            float inv = rcpf(1.0f + c);
            avzp[k] = (1.0f - c) * inv;
            bvzp[k] = DT * INV_H * inv * rcpf(rpa[k]);
            c = 0.5f * DT * dma[k];
            inv = rcpf(1.0f + c);
            avzm[k] = (1.0f - c) * inv;
            bvzm[k] = DT * INV_H * inv * rcpf(rma[k]);
        }
    }
    float q1[4], q2[4], q3[4], a_s[4];
    {
        const float4 vp4 = ld4(vp + rz + xg), vs4 = ld4(vs + rz + xg);
        const float vpa[4] = {vp4.x, vp4.y, vp4.z, vp4.w};
        const float vsa[4] = {vs4.x, vs4.y, vs4.z, vs4.w};
        #pragma unroll
        for (int k = 0; k < 4; ++k) {
            const float r   = rz6[k + 1];
            const float muv = r * vsa[k] * vsa[k];
            const float lam = r * vpa[k] * vpa[k] - 2.0f * muv;
            const float bsH = DT * INV_H * inv_c[k];
            q1[k] = bsH * (lam + 2.0f * muv);
            q2[k] = bsH * lam;
            q3[k] = bsH * muv;
            a_s[k] = avz[k + 1];
        }
    }

    // --- new velocities (leapfrog: from old stresses) ---
    float vxn_z[5];                 // vx_new(z, xg+k), k=0..4
    #pragma unroll
    for (int k = 0; k < 5; ++k)
        vxn_z[k] = avz[k + 1] * vxz[k]
                 + bvz[k + 1] * ((txxz[k + 1] - txxz[k])
                               + (txzz[k + 1] - txzzm[k]));
    float vzn_z[5];                 // vz_new(z, xg-1+k), k=0..4
    #pragma unroll
    for (int k = 0; k < 5; ++k)
        vzn_z[k] = avz[k] * vzz[k]
                 + bvz[k] * ((txzz[k + 1] - txzz[k])
                           + (tzzzp[k] - tzzz[k]));
    float vxn_zp[4];                // vx_new(zp, xg+k)
    #pragma unroll
    for (int k = 0; k < 4; ++k)
        vxn_zp[k] = avzp[k] * vxzp[k]
                  + bvzp[k] * ((txxzp[k + 1] - txxzp[k])
                             + (txzzp[k] - txzz[k + 1]));
    float vzn_zm[4];                // vz_new(zm, xg+k)
    #pragma unroll
    for (int k = 0; k < 4; ++k)
        vzn_zm[k] = avzm[k] * vzzm[k]
                  + bvzm[k] * ((txzzm[k + 1] - txzzm[k])
                             + (tzzz[k + 1] - tzzzm[k]));

    // --- stress update (from new velocities) ---
    float oxx[4], ozz[4], oxz[4];
    #pragma unroll
    for (int k = 0; k < 4; ++k) {
        const float dvx = vxn_z[k + 1] - vxn_z[k];          // d+x vx_new
        const float dvz = vzn_z[k + 1] - vzn_zm[k];         // d-z vz_new
        oxx[k] = a_s[k] * txxz[k + 1] + q1[k] * dvx + q2[k] * dvz;
        ozz[k] = a_s[k] * tzzz[k + 1] + q1[k] * dvz + q2[k] * dvx;
        oxz[k] = a_s[k] * txzz[k + 1]
               + q3[k] * ((vxn_zp[k] - vxn_z[k])
                        + (vzn_z[k + 1] - vzn_z[k]));
    }

    st_nt4(out + 0 * VOL + cz, vxn_z[0], vxn_z[1], vxn_z[2], vxn_z[3]);
    st_nt4(out + 1 * VOL + cz, vzn_z[1], vzn_z[2], vzn_z[3], vzn_z[4]);
    st_nt4(out + 2 * VOL + cz, oxx[0], oxx[1], oxx[2], oxx[3]);
    st_nt4(out + 3 * VOL + cz, ozz[0], ozz[1], ozz[2], ozz[3]);
    st_nt4(out + 4 * VOL + cz, oxz[0], oxz[1], oxz[2], oxz[3]);
}

extern "C" void kernel_launch(void* const* d_in, const int* in_sizes, int n_in,
                              void* d_out, int out_size, void* d_ws, size_t ws_size,
                              hipStream_t stream) {
    const float* vp  = (const float*)d_in[0];
    const float* vs  = (const float*)d_in[1];
    const float* rho = (const float*)d_in[2];
    const float* vx  = (const float*)d_in[3];
    const float* vz  = (const float*)d_in[4];
    const float* txx = (const float*)d_in[5];
    const float* tzz = (const float*)d_in[6];
    const float* txz = (const float*)d_in[7];
    const float* dd  = (const float*)d_in[8];
    float* out = (float*)d_out;

    const int threads = 256;
    const int blocks  = NBLK;  // 16384, exact
    hipLaunchKernelGGL(wave_fused_v5, dim3(blocks), dim3(threads), 0, stream,
                       vp, vs, rho, vx, vz, txx, tzz, txz, dd, out);
}

// Round 6
// 752.811 us; speedup vs baseline: 1.0030x; 1.0030x over previous
//
#include <hip/hip_runtime.h>

// WaveCell v6: 2D staggered-grid elastic FDTD timestep, fused single kernel.
// B=4, NZ=NX=2048, fp32, periodic wrap (pow2 dims).
//
// History:
//  v2 (212us): thread=4x*4shots, no swizzle. 817MB @ 3.85 TB/s.
//  v3 (253us): +swizzle +unroll2 -> unroll2 regression.
//  v4 (213us): swizzle+unroll1. 539MB @ 2.53 TB/s. Time == v2 despite 2.4x
//      less HBM traffic -> limit is waves*MLP/latency (Little's law), not BW.
//      VGPR 68 is 4 regs over the 64-reg occupancy cliff (m69: waves/CU
//      halve at 64/128/256) -> only ~10 waves/CU resident.
//  v5 (343us): 1 shot/thread + loads-hoisted + bounds(256,8): compiler
//      spilled to VGPR 32 (WRITE +240MiB scratch, FETCH +288MB). Lesson:
//      occupancy bought with scratch is worthless; keep v4's schedule.
//  v6: v4 body + register diet (drop a_s[] copy, drop inv_c[] -- recompute
//      rcp in q-loop; VALU 9% busy = free) + __launch_bounds__(256,8) to pin
//      VGPR<=64 -> 32-wave/CU budget. Verify no spill via WRITE_SIZE==320MiB.

constexpr int NZ = 2048;
constexpr int NX = 2048;
constexpr int B  = 4;
constexpr int PLANE = NZ * NX;      // 4,194,304
constexpr int VOL   = B * PLANE;    // 16,777,216
constexpr float DT    = 1e-3f;
constexpr float INV_H = 0.1f;       // 1/10m
constexpr int NBLK  = (PLANE / 4) / 256;   // 4096
constexpr int NXCD  = 8;
constexpr int BLK_PER_XCD = NBLK / NXCD;   // 512

typedef float f32x4 __attribute__((ext_vector_type(4)));

__device__ __forceinline__ float rcpf(float x) { return __builtin_amdgcn_rcpf(x); }
__device__ __forceinline__ float4 ld4(const float* __restrict__ p) {
    return *reinterpret_cast<const float4*>(p);
}
__device__ __forceinline__ void st_nt4(float* __restrict__ p,
                                       float a, float b, float c, float d) {
    f32x4 v = {a, b, c, d};
    __builtin_nontemporal_store(v, reinterpret_cast<f32x4*>(p));
}

__global__ __launch_bounds__(256, 8) void wave_fused_v6(
    const float* __restrict__ vp,  const float* __restrict__ vs,
    const float* __restrict__ rho,
    const float* __restrict__ vx,  const float* __restrict__ vz,
    const float* __restrict__ txx, const float* __restrict__ tzz,
    const float* __restrict__ txz,
    const float* __restrict__ dd,
    float* __restrict__ out)
{
    // XCD-band swizzle: XCD k owns contiguous blocks [k*512,(k+1)*512) ->
    // each XCD streams a 256-row z-band; halo rows hit its private L2.
    const int bid = blockIdx.x;
    const int sb  = (bid & (NXCD - 1)) * BLK_PER_XCD + (bid >> 3);
    const int t   = sb * blockDim.x + threadIdx.x;          // [0, PLANE/4)
    const int xg = (t & (NX / 4 - 1)) << 2;                 // x base, %4==0
    const int z  = t >> 9;                                  // t / (NX/4)
    const int zp = (z + 1) & (NZ - 1);
    const int zm = (z - 1) & (NZ - 1);
    const int xm1 = (xg - 1) & (NX - 1);
    const int xp4 = (xg + 4) & (NX - 1);
    const int rz  = z  * NX;
    const int rzp = zp * NX;
    const int rzm = zm * NX;

    // ---------- 2D coefficient setup (amortized over B=4 shots) ----------
    float dz6[6], rz6[6];
    {
        const float4 d4 = ld4(dd + rz + xg);
        dz6[0] = dd[rz + xm1]; dz6[1] = d4.x; dz6[2] = d4.y;
        dz6[3] = d4.z;         dz6[4] = d4.w; dz6[5] = dd[rz + xp4];
        const float4 r4 = ld4(rho + rz + xg);
        rz6[0] = rho[rz + xm1]; rz6[1] = r4.x; rz6[2] = r4.y;
        rz6[3] = r4.z;          rz6[4] = r4.w; rz6[5] = rho[rz + xp4];
    }
    float avz[6], bvz[6];
    #pragma unroll
    for (int j = 0; j < 6; ++j) {
        const float c   = 0.5f * DT * dz6[j];
        const float inv = rcpf(1.0f + c);
        avz[j] = (1.0f - c) * inv;
        bvz[j] = DT * INV_H * inv * rcpf(rz6[j]);
    }
    float avzp[4], bvzp[4], avzm[4], bvzm[4];
    {
        const float4 dp = ld4(dd + rzp + xg), dm = ld4(dd + rzm + xg);
        const float4 rp = ld4(rho + rzp + xg), rm = ld4(rho + rzm + xg);
        const float dpa[4] = {dp.x, dp.y, dp.z, dp.w};
        const float dma[4] = {dm.x, dm.y, dm.z, dm.w};
        const float rpa[4] = {rp.x, rp.y, rp.z, rp.w};
        const float rma[4] = {rm.x, rm.y, rm.z, rm.w};
        #pragma unroll
        for (int k = 0; k < 4; ++k) {
            float c = 0.5f * DT * dpa[k];
            float inv = rcpf(1.0f + c);
            avzp[k] = (1.0f - c) * inv;
            bvzp[k] = DT * INV_H * inv * rcpf(rpa[k]);
            c = 0.5f * DT * dma[k];
            inv = rcpf(1.0f + c);
            avzm[k] = (1.0f - c) * inv;
            bvzm[k] = DT * INV_H * inv * rcpf(rma[k]);
        }
    }
    float q1[4], q2[4], q3[4];
    {
        const float4 vp4 = ld4(vp + rz + xg), vs4 = ld4(vs + rz + xg);
        const float vpa[4] = {vp4.x, vp4.y, vp4.z, vp4.w};
        const float vsa[4] = {vs4.x, vs4.y, vs4.z, vs4.w};
        #pragma unroll
        for (int k = 0; k < 4; ++k) {
            const float r   = rz6[k + 1];
            const float muv = r * vsa[k] * vsa[k];
            const float lam = r * vpa[k] * vpa[k] - 2.0f * muv;
            // recompute inv(1+c) here instead of caching inv_c[] (reg diet;
            // 4 extra quarter-rate rcps vs a 9%-busy VALU = free)
            const float inv = rcpf(1.0f + 0.5f * DT * dz6[k + 1]);
            const float bsH = DT * INV_H * inv;
            q1[k] = bsH * (lam + 2.0f * muv);
            q2[k] = bsH * lam;
            q3[k] = bsH * muv;
        }
    }

    // ---------- per-shot field update ----------
    #pragma unroll 1   // v4 scheduling: per-shot burst of loads, one drain
    for (int b = 0; b < B; ++b) {
        const int b3  = b * PLANE;
        const int cz  = b3 + rz  + xg;
        const int czp = b3 + rzp + xg;
        const int czm = b3 + rzm + xg;

        // row segments (array index j <-> column xg-1+j unless noted)
        float txxz[6], txzz[6], tzzz[5], tzzzp[5], txxzp[5];
        float txzzm[5];                 // index k <-> column xg+k
        float vxz[5];                   // index k <-> column xg+k
        float vzz[5];                   // index j <-> column xg-1+j
        {
            float4 m;
            m = ld4(txx + cz);
            txxz[1] = m.x; txxz[2] = m.y; txxz[3] = m.z; txxz[4] = m.w;
            txxz[0] = txx[b3 + rz + xm1];  txxz[5] = txx[b3 + rz + xp4];
            m = ld4(txz + cz);
            txzz[1] = m.x; txzz[2] = m.y; txzz[3] = m.z; txzz[4] = m.w;
            txzz[0] = txz[b3 + rz + xm1];  txzz[5] = txz[b3 + rz + xp4];
            m = ld4(tzz + cz);
            tzzz[1] = m.x; tzzz[2] = m.y; tzzz[3] = m.z; tzzz[4] = m.w;
            tzzz[0] = tzz[b3 + rz + xm1];
            m = ld4(tzz + czp);
            tzzzp[1] = m.x; tzzzp[2] = m.y; tzzzp[3] = m.z; tzzzp[4] = m.w;
            tzzzp[0] = tzz[b3 + rzp + xm1];
            m = ld4(txx + czp);
            txxzp[1] = m.x; txxzp[2] = m.y; txxzp[3] = m.z; txxzp[4] = m.w;
            txxzp[0] = txx[b3 + rzp + xm1];
            m = ld4(txz + czm);
            txzzm[0] = m.x; txzzm[1] = m.y; txzzm[2] = m.z; txzzm[3] = m.w;
            txzzm[4] = txz[b3 + rzm + xp4];
            m = ld4(vx + cz);
            vxz[0] = m.x; vxz[1] = m.y; vxz[2] = m.z; vxz[3] = m.w;
            vxz[4] = vx[b3 + rz + xp4];
            m = ld4(vz + cz);
            vzz[1] = m.x; vzz[2] = m.y; vzz[3] = m.z; vzz[4] = m.w;
            vzz[0] = vz[b3 + rz + xm1];
        }
        const float4 tp4 = ld4(txz + czp);   // txz row zp, cols xg..xg+3
        const float4 tm4 = ld4(tzz + czm);   // tzz row zm, cols xg..xg+3
        const float4 vxp4 = ld4(vx + czp);   // vx  row zp, cols xg..xg+3
        const float4 vzm4 = ld4(vz + czm);   // vz  row zm, cols xg..xg+3
        const float txzzp[4] = {tp4.x, tp4.y, tp4.z, tp4.w};
        const float tzzzm[4] = {tm4.x, tm4.y, tm4.z, tm4.w};
        const float vxzp[4]  = {vxp4.x, vxp4.y, vxp4.z, vxp4.w};
        const float vzzm[4]  = {vzm4.x, vzm4.y, vzm4.z, vzm4.w};

        // --- new velocities (leapfrog: from old stresses) ---
        float vxn_z[5];                 // vx_new(z, xg+k), k=0..4
        #pragma unroll
        for (int k = 0; k < 5; ++k)
            vxn_z[k] = avz[k + 1] * vxz[k]
                     + bvz[k + 1] * ((txxz[k + 1] - txxz[k])
                                   + (txzz[k + 1] - txzzm[k]));
        float vzn_z[5];                 // vz_new(z, xg-1+k), k=0..4
        #pragma unroll
        for (int k = 0; k < 5; ++k)
            vzn_z[k] = avz[k] * vzz[k]
                     + bvz[k] * ((txzz[k + 1] - txzz[k])
                               + (tzzzp[k] - tzzz[k]));
        float vxn_zp[4];                // vx_new(zp, xg+k)
        #pragma unroll
        for (int k = 0; k < 4; ++k)
            vxn_zp[k] = avzp[k] * vxzp[k]
                      + bvzp[k] * ((txxzp[k + 1] - txxzp[k])
                                 + (txzzp[k] - txzz[k + 1]));
        float vzn_zm[4];                // vz_new(zm, xg+k)
        #pragma unroll
        for (int k = 0; k < 4; ++k)
            vzn_zm[k] = avzm[k] * vzzm[k]
                      + bvzm[k] * ((txzzm[k + 1] - txzzm[k])
                                 + (tzzz[k + 1] - tzzzm[k]));

        // --- stress update (from new velocities) ---
        float oxx[4], ozz[4], oxz[4];
        #pragma unroll
        for (int k = 0; k < 4; ++k) {
            const float dvx = vxn_z[k + 1] - vxn_z[k];          // d+x vx_new
            const float dvz = vzn_z[k + 1] - vzn_zm[k];         // d-z vz_new
            oxx[k] = avz[k + 1] * txxz[k + 1] + q1[k] * dvx + q2[k] * dvz;
            ozz[k] = avz[k + 1] * tzzz[k + 1] + q1[k] * dvz + q2[k] * dvx;
            oxz[k] = avz[k + 1] * txzz[k + 1]
                   + q3[k] * ((vxn_zp[k] - vxn_z[k])
                            + (vzn_z[k + 1] - vzn_z[k]));
        }

        st_nt4(out + 0 * VOL + cz, vxn_z[0], vxn_z[1], vxn_z[2], vxn_z[3]);
        st_nt4(out + 1 * VOL + cz, vzn_z[1], vzn_z[2], vzn_z[3], vzn_z[4]);
        st_nt4(out + 2 * VOL + cz, oxx[0], oxx[1], oxx[2], oxx[3]);
        st_nt4(out + 3 * VOL + cz, ozz[0], ozz[1], ozz[2], ozz[3]);
        st_nt4(out + 4 * VOL + cz, oxz[0], oxz[1], oxz[2], oxz[3]);
    }
}

extern "C" void kernel_launch(void* const* d_in, const int* in_sizes, int n_in,
                              void* d_out, int out_size, void* d_ws, size_t ws_size,
                              hipStream_t stream) {
    const float* vp  = (const float*)d_in[0];
    const float* vs  = (const float*)d_in[1];
    const float* rho = (const float*)d_in[2];
    const float* vx  = (const float*)d_in[3];
    const float* vz  = (const float*)d_in[4];
    const float* txx = (const float*)d_in[5];
    const float* tzz = (const float*)d_in[6];
    const float* txz = (const float*)d_in[7];
    const float* dd  = (const float*)d_in[8];
    float* out = (float*)d_out;

    const int threads = 256;
    const int blocks  = NBLK;  // 4096, exact
    hipLaunchKernelGGL(wave_fused_v6, dim3(blocks), dim3(threads), 0, stream,
                       vp, vs, rho, vx, vz, txx, tzz, txz, dd, out);
}

// Round 7
// 632.421 us; speedup vs baseline: 1.1940x; 1.1904x over previous
//
#include <hip/hip_runtime.h>

// WaveCell v7: 2D staggered-grid elastic FDTD timestep, fused single kernel.
// B=4, NZ=NX=2048, fp32, periodic wrap (pow2 dims).
//
// History:
//  v2 (212us): thread=4x*4shots. 817MB @ 3.85 TB/s, VGPR 68, occ 32%.
//  v4 (213us): +XCD swizzle. 539MB @ 2.53 TB/s. Time == v2 despite 2.4x less
//      HBM traffic -> concurrency-limited (Little's law), not BW-limited.
//      VGPR 68 = 4 over the 64-reg tier (m69: wave budget halves at 64/128).
//  v5/v6 (343us): __launch_bounds__(256,8) FORCED 8 waves/EU -> compiler
//      allocated 32 VGPR and spilled (WRITE +160MiB, FETCH +590MB). Lesson:
//      never force occupancy past the live set; shrink the live set instead.
//  v7: structural register diet, no forcing:
//      - zp/zm velocity coeffs (16 persistent regs in v4) recomputed per
//        shot from dd/rho rows zp/zm: loads are L1-hot (same lines each
//        shot), ~20 VALU/shot vs 5-9% VALUBusy = free. asm launder on the
//        row offsets blocks LICM from re-hoisting (which would restore the
//        16-reg liveness).
//      - q1/q2/q3 fused into the main coeff loop (kills inv_c/a_s copies,
//        shortens dz/rz/vp/vs lifetimes).
//      Persistent coeffs 44 -> 24 regs; predict VGPR 52-60 -> natural
//      <=64 tier -> 2x wave budget. Verify no spill: WRITE_SIZE == 320MiB.

constexpr int NZ = 2048;
constexpr int NX = 2048;
constexpr int B  = 4;
constexpr int PLANE = NZ * NX;      // 4,194,304
constexpr int VOL   = B * PLANE;    // 16,777,216
constexpr float DT    = 1e-3f;
constexpr float INV_H = 0.1f;       // 1/10m
constexpr int NBLK  = (PLANE / 4) / 256;   // 4096
constexpr int NXCD  = 8;
constexpr int BLK_PER_XCD = NBLK / NXCD;   // 512

typedef float f32x4 __attribute__((ext_vector_type(4)));

__device__ __forceinline__ float rcpf(float x) { return __builtin_amdgcn_rcpf(x); }
__device__ __forceinline__ float4 ld4(const float* __restrict__ p) {
    return *reinterpret_cast<const float4*>(p);
}
__device__ __forceinline__ void st_nt4(float* __restrict__ p,
                                       float a, float b, float c, float d) {
    f32x4 v = {a, b, c, d};
    __builtin_nontemporal_store(v, reinterpret_cast<f32x4*>(p));
}

__global__ __launch_bounds__(256) void wave_fused_v7(
    const float* __restrict__ vp,  const float* __restrict__ vs,
    const float* __restrict__ rho,
    const float* __restrict__ vx,  const float* __restrict__ vz,
    const float* __restrict__ txx, const float* __restrict__ tzz,
    const float* __restrict__ txz,
    const float* __restrict__ dd,
    float* __restrict__ out)
{
    // XCD-band swizzle: XCD k owns contiguous blocks [k*512,(k+1)*512) ->
    // each XCD streams a 256-row z-band; halo rows hit its private L2.
    const int bid = blockIdx.x;
    const int sb  = (bid & (NXCD - 1)) * BLK_PER_XCD + (bid >> 3);
    const int t   = sb * blockDim.x + threadIdx.x;          // [0, PLANE/4)
    const int xg = (t & (NX / 4 - 1)) << 2;                 // x base, %4==0
    const int z  = t >> 9;                                  // t / (NX/4)
    const int zp = (z + 1) & (NZ - 1);
    const int zm = (z - 1) & (NZ - 1);
    const int xm1 = (xg - 1) & (NX - 1);
    const int xp4 = (xg + 4) & (NX - 1);
    const int rz  = z  * NX;
    const int rzp = zp * NX;
    const int rzm = zm * NX;

    // ---------- row-z coefficients + stress premultipliers (24 regs live) ----
    float avz[6], bvz[6], q1[4], q2[4], q3[4];
    {
        const float4 d4  = ld4(dd  + rz + xg);
        const float4 r4  = ld4(rho + rz + xg);
        const float4 vp4 = ld4(vp  + rz + xg);
        const float4 vs4 = ld4(vs  + rz + xg);
        const float dza[4] = {d4.x, d4.y, d4.z, d4.w};
        const float rza[4] = {r4.x, r4.y, r4.z, r4.w};
        const float vpa[4] = {vp4.x, vp4.y, vp4.z, vp4.w};
        const float vsa[4] = {vs4.x, vs4.y, vs4.z, vs4.w};
        #pragma unroll
        for (int k = 0; k < 4; ++k) {
            const float c   = 0.5f * DT * dza[k];
            const float inv = rcpf(1.0f + c);
            avz[k + 1] = (1.0f - c) * inv;
            const float bH = DT * INV_H * inv;
            bvz[k + 1] = bH * rcpf(rza[k]);
            const float muv = rza[k] * vsa[k] * vsa[k];
            const float lam = rza[k] * vpa[k] * vpa[k] - 2.0f * muv;
            q1[k] = bH * (lam + 2.0f * muv);
            q2[k] = bH * lam;
            q3[k] = bH * muv;
        }
        {   const float dv = dd[rz + xm1], rv = rho[rz + xm1];
            const float c = 0.5f * DT * dv;
            const float inv = rcpf(1.0f + c);
            avz[0] = (1.0f - c) * inv;
            bvz[0] = DT * INV_H * inv * rcpf(rv); }
        {   const float dv = dd[rz + xp4], rv = rho[rz + xp4];
            const float c = 0.5f * DT * dv;
            const float inv = rcpf(1.0f + c);
            avz[5] = (1.0f - c) * inv;
            bvz[5] = DT * INV_H * inv * rcpf(rv); }
    }

    // ---------- per-shot field update ----------
    #pragma unroll 1   // per-shot burst of loads, one drain
    for (int b = 0; b < B; ++b) {
        const int b3  = b * PLANE;
        const int cz  = b3 + rz  + xg;
        const int czp = b3 + rzp + xg;
        const int czm = b3 + rzm + xg;

        // Launder zp/zm row offsets: the dd/rho coefficient loads below are
        // loop-invariant; without this LICM hoists them and re-creates the
        // 16 persistent coeff registers this version exists to eliminate.
        int rzp_c = rzp, rzm_c = rzm;
        asm volatile("" : "+v"(rzp_c), "+v"(rzm_c));
        const float4 dp4 = ld4(dd  + rzp_c + xg);
        const float4 rp4 = ld4(rho + rzp_c + xg);
        const float4 dm4 = ld4(dd  + rzm_c + xg);
        const float4 rm4 = ld4(rho + rzm_c + xg);

        // row segments (array index j <-> column xg-1+j unless noted)
        float txxz[6], txzz[6], tzzz[5], tzzzp[5], txxzp[5];
        float txzzm[5];                 // index k <-> column xg+k
        float vxz[5];                   // index k <-> column xg+k
        float vzz[5];                   // index j <-> column xg-1+j
        {
            float4 m;
            m = ld4(txx + cz);
            txxz[1] = m.x; txxz[2] = m.y; txxz[3] = m.z; txxz[4] = m.w;
            txxz[0] = txx[b3 + rz + xm1];  txxz[5] = txx[b3 + rz + xp4];
            m = ld4(txz + cz);
            txzz[1] = m.x; txzz[2] = m.y; txzz[3] = m.z; txzz[4] = m.w;
            txzz[0] = txz[b3 + rz + xm1];  txzz[5] = txz[b3 + rz + xp4];
            m = ld4(tzz + cz);
            tzzz[1] = m.x; tzzz[2] = m.y; tzzz[3] = m.z; tzzz[4] = m.w;
            tzzz[0] = tzz[b3 + rz + xm1];
            m = ld4(tzz + czp);
            tzzzp[1] = m.x; tzzzp[2] = m.y; tzzzp[3] = m.z; tzzzp[4] = m.w;
            tzzzp[0] = tzz[b3 + rzp + xm1];
            m = ld4(txx + czp);
            txxzp[1] = m.x; txxzp[2] = m.y; txxzp[3] = m.z; txxzp[4] = m.w;
            txxzp[0] = txx[b3 + rzp + xm1];
            m = ld4(txz + czm);
            txzzm[0] = m.x; txzzm[1] = m.y; txzzm[2] = m.z; txzzm[3] = m.w;
            txzzm[4] = txz[b3 + rzm + xp4];
            m = ld4(vx + cz);
            vxz[0] = m.x; vxz[1] = m.y; vxz[2] = m.z; vxz[3] = m.w;
            vxz[4] = vx[b3 + rz + xp4];
            m = ld4(vz + cz);
            vzz[1] = m.x; vzz[2] = m.y; vzz[3] = m.z; vzz[4] = m.w;
            vzz[0] = vz[b3 + rz + xm1];
        }
        const float4 tp4  = ld4(txz + czp);  // txz row zp, cols xg..xg+3
        const float4 tm4  = ld4(tzz + czm);  // tzz row zm, cols xg..xg+3
        const float4 vxp4 = ld4(vx + czp);   // vx  row zp, cols xg..xg+3
        const float4 vzm4 = ld4(vz + czm);   // vz  row zm, cols xg..xg+3
        const float txzzp[4] = {tp4.x, tp4.y, tp4.z, tp4.w};
        const float tzzzm[4] = {tm4.x, tm4.y, tm4.z, tm4.w};
        const float vxzp[4]  = {vxp4.x, vxp4.y, vxp4.z, vxp4.w};
        const float vzzm[4]  = {vzm4.x, vzm4.y, vzm4.z, vzm4.w};

        // zp/zm velocity coefficients, recomputed per shot (transient regs)
        float azp[4], bzp[4], azm[4], bzm[4];
        {
            const float dpa[4] = {dp4.x, dp4.y, dp4.z, dp4.w};
            const float dma[4] = {dm4.x, dm4.y, dm4.z, dm4.w};
            const float rpa[4] = {rp4.x, rp4.y, rp4.z, rp4.w};
            const float rma[4] = {rm4.x, rm4.y, rm4.z, rm4.w};
            #pragma unroll
            for (int k = 0; k < 4; ++k) {
                float c = 0.5f * DT * dpa[k];
                float inv = rcpf(1.0f + c);
                azp[k] = (1.0f - c) * inv;
                bzp[k] = DT * INV_H * inv * rcpf(rpa[k]);
                c = 0.5f * DT * dma[k];
                inv = rcpf(1.0f + c);
                azm[k] = (1.0f - c) * inv;
                bzm[k] = DT * INV_H * inv * rcpf(rma[k]);
            }
        }

        // --- new velocities (leapfrog: from old stresses) ---
        float vxn_z[5];                 // vx_new(z, xg+k), k=0..4
        #pragma unroll
        for (int k = 0; k < 5; ++k)
            vxn_z[k] = avz[k + 1] * vxz[k]
                     + bvz[k + 1] * ((txxz[k + 1] - txxz[k])
                                   + (txzz[k + 1] - txzzm[k]));
        float vzn_z[5];                 // vz_new(z, xg-1+k), k=0..4
        #pragma unroll
        for (int k = 0; k < 5; ++k)
            vzn_z[k] = avz[k] * vzz[k]
                     + bvz[k] * ((txzz[k + 1] - txzz[k])
                               + (tzzzp[k] - tzzz[k]));
        float vxn_zp[4];                // vx_new(zp, xg+k)
        #pragma unroll
        for (int k = 0; k < 4; ++k)
            vxn_zp[k] = azp[k] * vxzp[k]
                      + bzp[k] * ((txxzp[k + 1] - txxzp[k])
                                + (txzzp[k] - txzz[k + 1]));
        float vzn_zm[4];                // vz_new(zm, xg+k)
        #pragma unroll
        for (int k = 0; k < 4; ++k)
            vzn_zm[k] = azm[k] * vzzm[k]
                      + bzm[k] * ((txzzm[k + 1] - txzzm[k])
                                + (tzzz[k + 1] - tzzzm[k]));

        // --- stress update (from new velocities) ---
        float oxx[4], ozz[4], oxz[4];
        #pragma unroll
        for (int k = 0; k < 4; ++k) {
            const float dvx = vxn_z[k + 1] - vxn_z[k];          // d+x vx_new
            const float dvz = vzn_z[k + 1] - vzn_zm[k];         // d-z vz_new
            oxx[k] = avz[k + 1] * txxz[k + 1] + q1[k] * dvx + q2[k] * dvz;
            ozz[k] = avz[k + 1] * tzzz[k + 1] + q1[k] * dvz + q2[k] * dvx;
            oxz[k] = avz[k + 1] * txzz[k + 1]
                   + q3[k] * ((vxn_zp[k] - vxn_z[k])
                            + (vzn_z[k + 1] - vzn_z[k]));
        }

        st_nt4(out + 0 * VOL + cz, vxn_z[0], vxn_z[1], vxn_z[2], vxn_z[3]);
        st_nt4(out + 1 * VOL + cz, vzn_z[1], vzn_z[2], vzn_z[3], vzn_z[4]);
        st_nt4(out + 2 * VOL + cz, oxx[0], oxx[1], oxx[2], oxx[3]);
        st_nt4(out + 3 * VOL + cz, ozz[0], ozz[1], ozz[2], ozz[3]);
        st_nt4(out + 4 * VOL + cz, oxz[0], oxz[1], oxz[2], oxz[3]);
    }
}

extern "C" void kernel_launch(void* const* d_in, const int* in_sizes, int n_in,
                              void* d_out, int out_size, void* d_ws, size_t ws_size,
                              hipStream_t stream) {
    const float* vp  = (const float*)d_in[0];
    const float* vs  = (const float*)d_in[1];
    const float* rho = (const float*)d_in[2];
    const float* vx  = (const float*)d_in[3];
    const float* vz  = (const float*)d_in[4];
    const float* txx = (const float*)d_in[5];
    const float* tzz = (const float*)d_in[6];
    const float* txz = (const float*)d_in[7];
    const float* dd  = (const float*)d_in[8];
    float* out = (float*)d_out;

    const int threads = 256;
    const int blocks  = NBLK;  // 4096, exact
    hipLaunchKernelGGL(wave_fused_v7, dim3(blocks), dim3(threads), 0, stream,
                       vp, vs, rho, vx, vz, txx, tzz, txz, dd, out);
}

// Round 8
// 617.742 us; speedup vs baseline: 1.2224x; 1.0238x over previous
//
#include <hip/hip_runtime.h>

// WaveCell v8: 2D staggered-grid elastic FDTD timestep, fused single kernel.
// B=4, NZ=NX=2048, fp32, periodic wrap (pow2 dims).
//
// History:
//  v2 (212us): thread=4x*4shots. 817MB @ 3.85 TB/s.
//  v4 (213us): +XCD swizzle. 539MB @ 2.53 TB/s. Time invariant to hit level.
//  v5/v6 (343us): forced occupancy -> spills. v7 (235us): reg diet failed
//      (VGPR stuck 68; laundered reloads added latency).
//  Evidence synthesis: v1 did 4.8x the VMEM instrs of v4 at only +28% time
//      -> NOT request-throughput bound. v6 hit 3.8 TB/s -> NOT fabric bound.
//      Remaining theory consistent with all rounds: per-shot vmcnt drain.
//      vmcnt retires IN ORDER; v4's loop order [loads_b][compute][stores_b]
//      [loads_b+1][wait loads_b+1] forces every shot to retire the previous
//      shot's 5 NT stores (HBM ack ~1000cy) before consuming its loads.
//  v8: store-defer-by-2 software pipeline, loads issued BEFORE deferred
//      stores: L0 C0 L1 C1 L2 S0 C2 L3 S1 C3 S2 S3. Every load-wait now has
//      only already-retired loads older than it (S0 older than L3-wait has a
//      full compute phase to drain). One load set live at a time; +2 output
//      buffers (40 floats). asm memory clobbers pin store-after-load order.
//      Everything else identical to v4 (swizzle, NT stores, coeffs).

constexpr int NZ = 2048;
constexpr int NX = 2048;
constexpr int B  = 4;
constexpr int PLANE = NZ * NX;      // 4,194,304
constexpr int VOL   = B * PLANE;    // 16,777,216
constexpr float DT    = 1e-3f;
constexpr float INV_H = 0.1f;       // 1/10m
constexpr int NBLK  = (PLANE / 4) / 256;   // 4096
constexpr int NXCD  = 8;
constexpr int BLK_PER_XCD = NBLK / NXCD;   // 512

typedef float f32x4 __attribute__((ext_vector_type(4)));

__device__ __forceinline__ float rcpf(float x) { return __builtin_amdgcn_rcpf(x); }
__device__ __forceinline__ float4 ld4(const float* __restrict__ p) {
    return *reinterpret_cast<const float4*>(p);
}
__device__ __forceinline__ void st_nt4(float* __restrict__ p,
                                       float a, float b, float c, float d) {
    f32x4 v = {a, b, c, d};
    __builtin_nontemporal_store(v, reinterpret_cast<f32x4*>(p));
}
#define MEM_ORDER() asm volatile("" ::: "memory")

struct LS {   // one shot's loaded row segments (statically indexed only)
    float txxz[6], txzz[6], tzzz[5], tzzzp[5], txxzp[5];
    float txzzm[5], vxz[5], vzz[5];
    float txzzp[4], tzzzm[4], vxzp[4], vzzm[4];
};
struct Out { f32x4 v[5]; };

__global__ __launch_bounds__(256) void wave_fused_v8(
    const float* __restrict__ vp,  const float* __restrict__ vs,
    const float* __restrict__ rho,
    const float* __restrict__ vx,  const float* __restrict__ vz,
    const float* __restrict__ txx, const float* __restrict__ tzz,
    const float* __restrict__ txz,
    const float* __restrict__ dd,
    float* __restrict__ out)
{
    // XCD-band swizzle: XCD k owns contiguous blocks [k*512,(k+1)*512) ->
    // each XCD streams a 256-row z-band; halo rows hit its private L2.
    const int bid = blockIdx.x;
    const int sb  = (bid & (NXCD - 1)) * BLK_PER_XCD + (bid >> 3);
    const int t   = sb * blockDim.x + threadIdx.x;          // [0, PLANE/4)
    const int xg = (t & (NX / 4 - 1)) << 2;                 // x base, %4==0
    const int z  = t >> 9;                                  // t / (NX/4)
    const int zp = (z + 1) & (NZ - 1);
    const int zm = (z - 1) & (NZ - 1);
    const int xm1 = (xg - 1) & (NX - 1);
    const int xp4 = (xg + 4) & (NX - 1);
    const int rz  = z  * NX;
    const int rzp = zp * NX;
    const int rzm = zm * NX;

    // ---------- 2D coefficient setup (amortized over B=4 shots) ----------
    float dz6[6], rz6[6];
    {
        const float4 d4 = ld4(dd + rz + xg);
        dz6[0] = dd[rz + xm1]; dz6[1] = d4.x; dz6[2] = d4.y;
        dz6[3] = d4.z;         dz6[4] = d4.w; dz6[5] = dd[rz + xp4];
        const float4 r4 = ld4(rho + rz + xg);
        rz6[0] = rho[rz + xm1]; rz6[1] = r4.x; rz6[2] = r4.y;
        rz6[3] = r4.z;          rz6[4] = r4.w; rz6[5] = rho[rz + xp4];
    }
    float avz[6], bvz[6], inv_c[4];
    #pragma unroll
    for (int j = 0; j < 6; ++j) {
        const float c   = 0.5f * DT * dz6[j];
        const float inv = rcpf(1.0f + c);
        avz[j] = (1.0f - c) * inv;
        bvz[j] = DT * INV_H * inv * rcpf(rz6[j]);
        if (j >= 1 && j <= 4) inv_c[j - 1] = inv;   // static after unroll
    }
    float avzp[4], bvzp[4], avzm[4], bvzm[4];
    {
        const float4 dp = ld4(dd + rzp + xg), dm = ld4(dd + rzm + xg);
        const float4 rp = ld4(rho + rzp + xg), rm = ld4(rho + rzm + xg);
        const float dpa[4] = {dp.x, dp.y, dp.z, dp.w};
        const float dma[4] = {dm.x, dm.y, dm.z, dm.w};
        const float rpa[4] = {rp.x, rp.y, rp.z, rp.w};
        const float rma[4] = {rm.x, rm.y, rm.z, rm.w};
        #pragma unroll
        for (int k = 0; k < 4; ++k) {
            float c = 0.5f * DT * dpa[k];
            float inv = rcpf(1.0f + c);
            avzp[k] = (1.0f - c) * inv;
            bvzp[k] = DT * INV_H * inv * rcpf(rpa[k]);
            c = 0.5f * DT * dma[k];
            inv = rcpf(1.0f + c);
            avzm[k] = (1.0f - c) * inv;
            bvzm[k] = DT * INV_H * inv * rcpf(rma[k]);
        }
    }
    float q1[4], q2[4], q3[4];
    {
        const float4 vp4 = ld4(vp + rz + xg), vs4 = ld4(vs + rz + xg);
        const float vpa[4] = {vp4.x, vp4.y, vp4.z, vp4.w};
        const float vsa[4] = {vs4.x, vs4.y, vs4.z, vs4.w};
        #pragma unroll
        for (int k = 0; k < 4; ++k) {
            const float r   = rz6[k + 1];
            const float muv = r * vsa[k] * vsa[k];
            const float lam = r * vpa[k] * vpa[k] - 2.0f * muv;
            const float bsH = DT * INV_H * inv_c[k];
            q1[k] = bsH * (lam + 2.0f * muv);
            q2[k] = bsH * lam;
            q3[k] = bsH * muv;
        }
    }

    auto load_shot = [&](int b, LS& L) {
        const int b3  = b * PLANE;
        const int cz  = b3 + rz  + xg;
        const int czp = b3 + rzp + xg;
        const int czm = b3 + rzm + xg;
        float4 m;
        m = ld4(txx + cz);
        L.txxz[1] = m.x; L.txxz[2] = m.y; L.txxz[3] = m.z; L.txxz[4] = m.w;
        L.txxz[0] = txx[b3 + rz + xm1];  L.txxz[5] = txx[b3 + rz + xp4];
        m = ld4(txz + cz);
        L.txzz[1] = m.x; L.txzz[2] = m.y; L.txzz[3] = m.z; L.txzz[4] = m.w;
        L.txzz[0] = txz[b3 + rz + xm1];  L.txzz[5] = txz[b3 + rz + xp4];
        m = ld4(tzz + cz);
        L.tzzz[1] = m.x; L.tzzz[2] = m.y; L.tzzz[3] = m.z; L.tzzz[4] = m.w;
        L.tzzz[0] = tzz[b3 + rz + xm1];
        m = ld4(tzz + czp);
        L.tzzzp[1] = m.x; L.tzzzp[2] = m.y; L.tzzzp[3] = m.z; L.tzzzp[4] = m.w;
        L.tzzzp[0] = tzz[b3 + rzp + xm1];
        m = ld4(txx + czp);
        L.txxzp[1] = m.x; L.txxzp[2] = m.y; L.txxzp[3] = m.z; L.txxzp[4] = m.w;
        L.txxzp[0] = txx[b3 + rzp + xm1];
        m = ld4(txz + czm);
        L.txzzm[0] = m.x; L.txzzm[1] = m.y; L.txzzm[2] = m.z; L.txzzm[3] = m.w;
        L.txzzm[4] = txz[b3 + rzm + xp4];
        m = ld4(vx + cz);
        L.vxz[0] = m.x; L.vxz[1] = m.y; L.vxz[2] = m.z; L.vxz[3] = m.w;
        L.vxz[4] = vx[b3 + rz + xp4];
        m = ld4(vz + cz);
        L.vzz[1] = m.x; L.vzz[2] = m.y; L.vzz[3] = m.z; L.vzz[4] = m.w;
        L.vzz[0] = vz[b3 + rz + xm1];
        m = ld4(txz + czp);
        L.txzzp[0] = m.x; L.txzzp[1] = m.y; L.txzzp[2] = m.z; L.txzzp[3] = m.w;
        m = ld4(tzz + czm);
        L.tzzzm[0] = m.x; L.tzzzm[1] = m.y; L.tzzzm[2] = m.z; L.tzzzm[3] = m.w;
        m = ld4(vx + czp);
        L.vxzp[0] = m.x; L.vxzp[1] = m.y; L.vxzp[2] = m.z; L.vxzp[3] = m.w;
        m = ld4(vz + czm);
        L.vzzm[0] = m.x; L.vzzm[1] = m.y; L.vzzm[2] = m.z; L.vzzm[3] = m.w;
    };

    auto compute_shot = [&](const LS& L, Out& o) {
        // --- new velocities (leapfrog: from old stresses) ---
        float vxn_z[5];                 // vx_new(z, xg+k), k=0..4
        #pragma unroll
        for (int k = 0; k < 5; ++k)
            vxn_z[k] = avz[k + 1] * L.vxz[k]
                     + bvz[k + 1] * ((L.txxz[k + 1] - L.txxz[k])
                                   + (L.txzz[k + 1] - L.txzzm[k]));
        float vzn_z[5];                 // vz_new(z, xg-1+k), k=0..4
        #pragma unroll
        for (int k = 0; k < 5; ++k)
            vzn_z[k] = avz[k] * L.vzz[k]
                     + bvz[k] * ((L.txzz[k + 1] - L.txzz[k])
                               + (L.tzzzp[k] - L.tzzz[k]));
        float vxn_zp[4];                // vx_new(zp, xg+k)
        #pragma unroll
        for (int k = 0; k < 4; ++k)
            vxn_zp[k] = avzp[k] * L.vxzp[k]
                      + bvzp[k] * ((L.txxzp[k + 1] - L.txxzp[k])
                                 + (L.txzzp[k] - L.txzz[k + 1]));
        float vzn_zm[4];                // vz_new(zm, xg+k)
        #pragma unroll
        for (int k = 0; k < 4; ++k)
            vzn_zm[k] = avzm[k] * L.vzzm[k]
                      + bvzm[k] * ((L.txzzm[k + 1] - L.txzzm[k])
                                 + (L.tzzz[k + 1] - L.tzzzm[k]));
        // --- stress update (from new velocities) ---
        float oxx[4], ozz[4], oxz[4];
        #pragma unroll
        for (int k = 0; k < 4; ++k) {
            const float dvx = vxn_z[k + 1] - vxn_z[k];          // d+x vx_new
            const float dvz = vzn_z[k + 1] - vzn_zm[k];         // d-z vz_new
            oxx[k] = avz[k + 1] * L.txxz[k + 1] + q1[k] * dvx + q2[k] * dvz;
            ozz[k] = avz[k + 1] * L.tzzz[k + 1] + q1[k] * dvz + q2[k] * dvx;
            oxz[k] = avz[k + 1] * L.txzz[k + 1]
                   + q3[k] * ((vxn_zp[k] - vxn_z[k])
                            + (vzn_z[k + 1] - vzn_z[k]));
        }
        o.v[0] = f32x4{vxn_z[0], vxn_z[1], vxn_z[2], vxn_z[3]};
        o.v[1] = f32x4{vzn_z[1], vzn_z[2], vzn_z[3], vzn_z[4]};
        o.v[2] = f32x4{oxx[0], oxx[1], oxx[2], oxx[3]};
        o.v[3] = f32x4{ozz[0], ozz[1], ozz[2], ozz[3]};
        o.v[4] = f32x4{oxz[0], oxz[1], oxz[2], oxz[3]};
    };

    auto store_shot = [&](const Out& o, int b) {
        const int cz = b * PLANE + rz + xg;
        #pragma unroll
        for (int k = 0; k < 5; ++k)
            __builtin_nontemporal_store(o.v[k],
                reinterpret_cast<f32x4*>(out + k * VOL + cz));
    };

    // Pipeline: L0 C0 L1 C1 L2 S0 C2 L3 S1 C3 S2 S3.
    // Every load burst precedes the stores issued in the same stage, so
    // in-order vmcnt retirement of a load set never requires an NT-store ack.
    LS L;
    Out o0, o1, o2, o3;
    load_shot(0, L);
    compute_shot(L, o0);
    load_shot(1, L);
    compute_shot(L, o1);
    load_shot(2, L);
    MEM_ORDER();            // keep S(o0) after the L2 burst
    store_shot(o0, 0);
    compute_shot(L, o2);
    load_shot(3, L);
    MEM_ORDER();            // keep S(o1) after the L3 burst
    store_shot(o1, 1);
    compute_shot(L, o3);
    store_shot(o2, 2);
    store_shot(o3, 3);
}

extern "C" void kernel_launch(void* const* d_in, const int* in_sizes, int n_in,
                              void* d_out, int out_size, void* d_ws, size_t ws_size,
                              hipStream_t stream) {
    const float* vp  = (const float*)d_in[0];
    const float* vs  = (const float*)d_in[1];
    const float* rho = (const float*)d_in[2];
    const float* vx  = (const float*)d_in[3];
    const float* vz  = (const float*)d_in[4];
    const float* txx = (const float*)d_in[5];
    const float* tzz = (const float*)d_in[6];
    const float* txz = (const float*)d_in[7];
    const float* dd  = (const float*)d_in[8];
    float* out = (float*)d_out;

    const int threads = 256;
    const int blocks  = NBLK;  // 4096, exact
    hipLaunchKernelGGL(wave_fused_v8, dim3(blocks), dim3(threads), 0, stream,
                       vp, vs, rho, vx, vz, txx, tzz, txz, dd, out);
}

// Round 9
// 609.189 us; speedup vs baseline: 1.2395x; 1.0140x over previous
//
#include <hip/hip_runtime.h>

// WaveCell v9: 2D staggered-grid elastic FDTD timestep, fused single kernel.
// B=4, NZ=NX=2048, fp32, periodic wrap (pow2 dims).
//
// History:
//  v2 (212us): thread=4x*4shots, float4 loads, NT stores.   WRITE@1.58 TB/s
//  v4 (213us): +XCD swizzle (FETCH 470->199MB, time flat).  WRITE@1.58 TB/s
//  v5/v6 (343us): forced-occupancy spills (+~170MB writes). WRITE@~1.6 TB/s
//  v8 (224us): store-defer pipeline, VGPR 88, occ 21%.      WRITE@1.50 TB/s
//  Synthesis: time tracks WRITE bytes at a pinned ~1.6 TB/s in EVERY fast
//  variant (335MB/1.58 = 212us = the wall; spill rounds 1.6x bytes = 1.6x
//  time), while read traffic varied 199->794MB with zero time effect.
//  Common factor: __builtin_nontemporal_store bypasses L2 -> write-through
//  dribble to HBM at ~1.6 TB/s. Never A/B-tested until now.
//
//  v9: v4 body exactly, with PLAIN cached float4 stores (dirty L2 lines,
//  bulk writeback at HBM rate). Single lever. Risk: streaming writes evict
//  halo-reuse lines (FETCH may rise 200->400MB) - fine if write rate 2x.

constexpr int NZ = 2048;
constexpr int NX = 2048;
constexpr int B  = 4;
constexpr int PLANE = NZ * NX;      // 4,194,304
constexpr int VOL   = B * PLANE;    // 16,777,216
constexpr float DT    = 1e-3f;
constexpr float INV_H = 0.1f;       // 1/10m
constexpr int NBLK  = (PLANE / 4) / 256;   // 4096
constexpr int NXCD  = 8;
constexpr int BLK_PER_XCD = NBLK / NXCD;   // 512

typedef float f32x4 __attribute__((ext_vector_type(4)));

__device__ __forceinline__ float rcpf(float x) { return __builtin_amdgcn_rcpf(x); }
__device__ __forceinline__ float4 ld4(const float* __restrict__ p) {
    return *reinterpret_cast<const float4*>(p);
}
__device__ __forceinline__ void st4(float* __restrict__ p,
                                    float a, float b, float c, float d) {
    f32x4 v = {a, b, c, d};
    *reinterpret_cast<f32x4*>(p) = v;   // plain cached store (via L2)
}

__global__ __launch_bounds__(256) void wave_fused_v9(
    const float* __restrict__ vp,  const float* __restrict__ vs,
    const float* __restrict__ rho,
    const float* __restrict__ vx,  const float* __restrict__ vz,
    const float* __restrict__ txx, const float* __restrict__ tzz,
    const float* __restrict__ txz,
    const float* __restrict__ dd,
    float* __restrict__ out)
{
    // XCD-band swizzle: XCD k owns contiguous blocks [k*512,(k+1)*512) ->
    // each XCD streams a 256-row z-band; halo rows hit its private L2.
    const int bid = blockIdx.x;
    const int sb  = (bid & (NXCD - 1)) * BLK_PER_XCD + (bid >> 3);
    const int t   = sb * blockDim.x + threadIdx.x;          // [0, PLANE/4)
    const int xg = (t & (NX / 4 - 1)) << 2;                 // x base, %4==0
    const int z  = t >> 9;                                  // t / (NX/4)
    const int zp = (z + 1) & (NZ - 1);
    const int zm = (z - 1) & (NZ - 1);
    const int xm1 = (xg - 1) & (NX - 1);
    const int xp4 = (xg + 4) & (NX - 1);
    const int rz  = z  * NX;
    const int rzp = zp * NX;
    const int rzm = zm * NX;

    // ---------- 2D coefficient setup (amortized over B=4 shots) ----------
    float dz6[6], rz6[6];
    {
        const float4 d4 = ld4(dd + rz + xg);
        dz6[0] = dd[rz + xm1]; dz6[1] = d4.x; dz6[2] = d4.y;
        dz6[3] = d4.z;         dz6[4] = d4.w; dz6[5] = dd[rz + xp4];
        const float4 r4 = ld4(rho + rz + xg);
        rz6[0] = rho[rz + xm1]; rz6[1] = r4.x; rz6[2] = r4.y;
        rz6[3] = r4.z;          rz6[4] = r4.w; rz6[5] = rho[rz + xp4];
    }
    float avz[6], bvz[6], inv_c[4];
    #pragma unroll
    for (int j = 0; j < 6; ++j) {
        const float c   = 0.5f * DT * dz6[j];
        const float inv = rcpf(1.0f + c);
        avz[j] = (1.0f - c) * inv;
        bvz[j] = DT * INV_H * inv * rcpf(rz6[j]);
        if (j >= 1 && j <= 4) inv_c[j - 1] = inv;   // static after unroll
    }
    float avzp[4], bvzp[4], avzm[4], bvzm[4];
    {
        const float4 dp = ld4(dd + rzp + xg), dm = ld4(dd + rzm + xg);
        const float4 rp = ld4(rho + rzp + xg), rm = ld4(rho + rzm + xg);
        const float dpa[4] = {dp.x, dp.y, dp.z, dp.w};
        const float dma[4] = {dm.x, dm.y, dm.z, dm.w};
        const float rpa[4] = {rp.x, rp.y, rp.z, rp.w};
        const float rma[4] = {rm.x, rm.y, rm.z, rm.w};
        #pragma unroll
        for (int k = 0; k < 4; ++k) {
            float c = 0.5f * DT * dpa[k];
            float inv = rcpf(1.0f + c);
            avzp[k] = (1.0f - c) * inv;
            bvzp[k] = DT * INV_H * inv * rcpf(rpa[k]);
            c = 0.5f * DT * dma[k];
            inv = rcpf(1.0f + c);
            avzm[k] = (1.0f - c) * inv;
            bvzm[k] = DT * INV_H * inv * rcpf(rma[k]);
        }
    }
    float q1[4], q2[4], q3[4];
    {
        const float4 vp4 = ld4(vp + rz + xg), vs4 = ld4(vs + rz + xg);
        const float vpa[4] = {vp4.x, vp4.y, vp4.z, vp4.w};
        const float vsa[4] = {vs4.x, vs4.y, vs4.z, vs4.w};
        #pragma unroll
        for (int k = 0; k < 4; ++k) {
            const float r   = rz6[k + 1];
            const float muv = r * vsa[k] * vsa[k];
            const float lam = r * vpa[k] * vpa[k] - 2.0f * muv;
            const float bsH = DT * INV_H * inv_c[k];
            q1[k] = bsH * (lam + 2.0f * muv);
            q2[k] = bsH * lam;
            q3[k] = bsH * muv;
        }
    }

    // ---------- per-shot field update ----------
    #pragma unroll 1   // per-shot burst of loads, one drain
    for (int b = 0; b < B; ++b) {
        const int b3  = b * PLANE;
        const int cz  = b3 + rz  + xg;
        const int czp = b3 + rzp + xg;
        const int czm = b3 + rzm + xg;

        // row segments (array index j <-> column xg-1+j unless noted)
        float txxz[6], txzz[6], tzzz[5], tzzzp[5], txxzp[5];
        float txzzm[5];                 // index k <-> column xg+k
        float vxz[5];                   // index k <-> column xg+k
        float vzz[5];                   // index j <-> column xg-1+j
        {
            float4 m;
            m = ld4(txx + cz);
            txxz[1] = m.x; txxz[2] = m.y; txxz[3] = m.z; txxz[4] = m.w;
            txxz[0] = txx[b3 + rz + xm1];  txxz[5] = txx[b3 + rz + xp4];
            m = ld4(txz + cz);
            txzz[1] = m.x; txzz[2] = m.y; txzz[3] = m.z; txzz[4] = m.w;
            txzz[0] = txz[b3 + rz + xm1];  txzz[5] = txz[b3 + rz + xp4];
            m = ld4(tzz + cz);
            tzzz[1] = m.x; tzzz[2] = m.y; tzzz[3] = m.z; tzzz[4] = m.w;
            tzzz[0] = tzz[b3 + rz + xm1];
            m = ld4(tzz + czp);
            tzzzp[1] = m.x; tzzzp[2] = m.y; tzzzp[3] = m.z; tzzzp[4] = m.w;
            tzzzp[0] = tzz[b3 + rzp + xm1];
            m = ld4(txx + czp);
            txxzp[1] = m.x; txxzp[2] = m.y; txxzp[3] = m.z; txxzp[4] = m.w;
            txxzp[0] = txx[b3 + rzp + xm1];
            m = ld4(txz + czm);
            txzzm[0] = m.x; txzzm[1] = m.y; txzzm[2] = m.z; txzzm[3] = m.w;
            txzzm[4] = txz[b3 + rzm + xp4];
            m = ld4(vx + cz);
            vxz[0] = m.x; vxz[1] = m.y; vxz[2] = m.z; vxz[3] = m.w;
            vxz[4] = vx[b3 + rz + xp4];
            m = ld4(vz + cz);
            vzz[1] = m.x; vzz[2] = m.y; vzz[3] = m.z; vzz[4] = m.w;
            vzz[0] = vz[b3 + rz + xm1];
        }
        const float4 tp4 = ld4(txz + czp);   // txz row zp, cols xg..xg+3
        const float4 tm4 = ld4(tzz + czm);   // tzz row zm, cols xg..xg+3
        const float4 vxp4 = ld4(vx + czp);   // vx  row zp, cols xg..xg+3
        const float4 vzm4 = ld4(vz + czm);   // vz  row zm, cols xg..xg+3
        const float txzzp[4] = {tp4.x, tp4.y, tp4.z, tp4.w};
        const float tzzzm[4] = {tm4.x, tm4.y, tm4.z, tm4.w};
        const float vxzp[4]  = {vxp4.x, vxp4.y, vxp4.z, vxp4.w};
        const float vzzm[4]  = {vzm4.x, vzm4.y, vzm4.z, vzm4.w};

        // --- new velocities (leapfrog: from old stresses) ---
        float vxn_z[5];                 // vx_new(z, xg+k), k=0..4
        #pragma unroll
        for (int k = 0; k < 5; ++k)
            vxn_z[k] = avz[k + 1] * vxz[k]
                     + bvz[k + 1] * ((txxz[k + 1] - txxz[k])
                                   + (txzz[k + 1] - txzzm[k]));
        float vzn_z[5];                 // vz_new(z, xg-1+k), k=0..4
        #pragma unroll
        for (int k = 0; k < 5; ++k)
            vzn_z[k] = avz[k] * vzz[k]
                     + bvz[k] * ((txzz[k + 1] - txzz[k])
                               + (tzzzp[k] - tzzz[k]));
        float vxn_zp[4];                // vx_new(zp, xg+k)
        #pragma unroll
        for (int k = 0; k < 4; ++k)
            vxn_zp[k] = avzp[k] * vxzp[k]
                      + bvzp[k] * ((txxzp[k + 1] - txxzp[k])
                                 + (txzzp[k] - txzz[k + 1]));
        float vzn_zm[4];                // vz_new(zm, xg+k)
        #pragma unroll
        for (int k = 0; k < 4; ++k)
            vzn_zm[k] = avzm[k] * vzzm[k]
                      + bvzm[k] * ((txzzm[k + 1] - txzzm[k])
                                 + (tzzz[k + 1] - tzzzm[k]));

        // --- stress update (from new velocities) ---
        float oxx[4], ozz[4], oxz[4];
        #pragma unroll
        for (int k = 0; k < 4; ++k) {
            const float dvx = vxn_z[k + 1] - vxn_z[k];          // d+x vx_new
            const float dvz = vzn_z[k + 1] - vzn_zm[k];         // d-z vz_new
            oxx[k] = avz[k + 1] * txxz[k + 1] + q1[k] * dvx + q2[k] * dvz;
            ozz[k] = avz[k + 1] * tzzz[k + 1] + q1[k] * dvz + q2[k] * dvx;
            oxz[k] = avz[k + 1] * txzz[k + 1]
                   + q3[k] * ((vxn_zp[k] - vxn_z[k])
                            + (vzn_z[k + 1] - vzn_z[k]));
        }

        st4(out + 0 * VOL + cz, vxn_z[0], vxn_z[1], vxn_z[2], vxn_z[3]);
        st4(out + 1 * VOL + cz, vzn_z[1], vzn_z[2], vzn_z[3], vzn_z[4]);
        st4(out + 2 * VOL + cz, oxx[0], oxx[1], oxx[2], oxx[3]);
        st4(out + 3 * VOL + cz, ozz[0], ozz[1], ozz[2], ozz[3]);
        st4(out + 4 * VOL + cz, oxz[0], oxz[1], oxz[2], oxz[3]);
    }
}

extern "C" void kernel_launch(void* const* d_in, const int* in_sizes, int n_in,
                              void* d_out, int out_size, void* d_ws, size_t ws_size,
                              hipStream_t stream) {
    const float* vp  = (const float*)d_in[0];
    const float* vs  = (const float*)d_in[1];
    const float* rho = (const float*)d_in[2];
    const float* vx  = (const float*)d_in[3];
    const float* vz  = (const float*)d_in[4];
    const float* txx = (const float*)d_in[5];
    const float* tzz = (const float*)d_in[6];
    const float* txz = (const float*)d_in[7];
    const float* dd  = (const float*)d_in[8];
    float* out = (float*)d_out;

    const int threads = 256;
    const int blocks  = NBLK;  // 4096, exact
    hipLaunchKernelGGL(wave_fused_v9, dim3(blocks), dim3(threads), 0, stream,
                       vp, vs, rho, vx, vz, txx, tzz, txz, dd, out);
}